// Round 15
// baseline (879.362 us; speedup 1.0000x reference)
//
#include <hip/hip_runtime.h>
#include <hip/hip_bf16.h>

#define Nn 8192
#define Tt 32
#define Ff 16
#define Hh 128
#define HEADS 4
#define Ee 2048
#define NNZ 65536
#define TF (Tt*Ff)       // 512
#define BN_EPS 1e-5f
#define MGRID 512        // 2 blocks/CU x 256 CUs: all co-resident by construction

// All float tensors are float32 per the reference.

typedef __attribute__((ext_vector_type(8))) short bf8_t;   // 8 bf16 lanes (4 VGPRs)
typedef __attribute__((ext_vector_type(4))) float f4_t;
typedef __attribute__((ext_vector_type(4))) short s4_t;
#define MFMA16(a,b,c) __builtin_amdgcn_mfma_f32_16x16x32_bf16(a,b,c,0,0,0)

__device__ __forceinline__ short f2bf(float v){
  union { __hip_bfloat16 h; short s; } u;
  u.h = __float2bfloat16(v);
  return u.s;
}
__device__ __forceinline__ float bf2f(short s){
  union { __hip_bfloat16 h; short s2; } u;
  u.s2 = s;
  return __bfloat162float(u.h);
}
__device__ __forceinline__ float fsigmoid(float x){
  return __builtin_amdgcn_rcpf(1.f + __expf(-x));
}
__device__ __forceinline__ float ftanh(float x){
  return 1.f - 2.f*__builtin_amdgcn_rcpf(__expf(2.f*x) + 1.f);
}
__device__ __forceinline__ float lrelu02(float x){ return (x >= 0.f) ? x : 0.2f*x; }

// ---------------- static scratch (fully rewritten every call) ----------------
__device__ __align__(16) short g_inxb[Nn*TF];   // bn1 output bf16, (T, N, F)
__device__ __align__(16) short g_hsb[Nn*Tt*Hh]; // GRU hidden states bf16, (N, T, H)
__device__ float  g_q[Nn*Hh];            // query = h31 @ Wq^T (gru epilogue)
__device__ float  g_cmb[Nn*2*Hh];        // [mixsum | q] per node
__device__ __align__(16) short g_nfb[Nn*Hh];     // nf bf16
__device__ __align__(16) short g_xwb[Nn*4*Hh];   // bn2(nf)@W1^T bf16, layout (n, c*4+hd)
__device__ __align__(16) short g_x1b[Nn*Hh];     // layer-1 node out, bf16
__device__ __align__(16) short g_xw2b[Nn*Hh];    // x1 @ W2^T, bf16
__device__ __align__(16) short g_eoutb[Ee*4*Hh]; // edge agg 1 bf16, layout (d, c*4+hd)
__device__ __align__(16) short g_eout2b[Ee*Hh];  // edge agg 2, bf16
__device__ float  g_px1[Nn*HEADS];       // att dots
__device__ float  g_pe1[Ee*HEADS];
__device__ float  g_pa2[Nn];
__device__ float  g_pb2[Ee];
__device__ float  g_m1[Nn*HEADS];        // per-(node,head) softmax max
__device__ float  g_is1[Nn*HEADS];       // per-(node,head) 1/(sum+eps)
__device__ float  g_m2[Nn];
__device__ float  g_is2[Nn];
__device__ float  g_w1x[HEADS*Hh];       // precomputed W^T-att folds
__device__ float  g_w1a[HEADS*Hh];
__device__ float  g_w2x[Hh];
__device__ float  g_w2a[Hh];
__device__ float  g_p1s[512*TF];         // bn1 partials
__device__ float  g_p1q[512*TF];
__device__ float  g_bn1s[TF], g_bn1b[TF];
__device__ float  g_bn2acc[256];         // [0:128) col sums of nf, [128:256) sumsq
__device__ unsigned g_bars[16];          // one-shot grid-barrier counters
__device__ int    g_D[Nn];
__device__ int    g_rowptr[Nn+1];
__device__ int    g_cursor[Nn];
__device__ int    g_eidx[NNZ];

// manual grid barrier: one counter per sync point, zeroed by k_pre each call.
// __syncthreads drains this block's vm writes (compiler emits vmcnt(0));
// atomics are device-scope (L2-coherent); trailing threadfence = acquire (L1 inv).
__device__ __forceinline__ void gsync(int idx){
  __syncthreads();
  if(threadIdx.x == 0){
    __threadfence();
    atomicAdd(&g_bars[idx], 1u);
    while(atomicAdd(&g_bars[idx], 0u) < (unsigned)MGRID){ __builtin_amdgcn_s_sleep(8); }
    __threadfence();
  }
  __syncthreads();
}

// ---------------- K1: bn1 partials + zero accums (0..511) | w-folds (512,513) ----------------
__global__ __launch_bounds__(256) void k_pre(const float* __restrict__ x,
                                             const float* __restrict__ W1,
                                             const float* __restrict__ att1,
                                             const float* __restrict__ W2,
                                             const float* __restrict__ att2){
  int b = blockIdx.x, tid = threadIdx.x;
  if(b >= 512){
    if(b == 512){
      for(int p = 0; p < 2; p++){
        int idx = p*256 + tid;           // 512 entries
        int hd = idx >> 7, k = idx & 127;
        float sx = 0.f, sa = 0.f;
        for(int c = 0; c < 128; c++){
          float wv = W1[(hd*128 + c)*128 + k];
          sx += wv*att1[hd*256 + c];
          sa += wv*att1[hd*256 + 128 + c];
        }
        g_w1x[idx] = sx; g_w1a[idx] = sa;
      }
    } else {
      int k = tid & 127;
      if(tid < 128){
        float s = 0.f;
        for(int c = 0; c < 128; c++) s += W2[c*128 + k]*att2[c];
        g_w2x[k] = s;
      } else {
        float s = 0.f;
        for(int c = 0; c < 128; c++) s += W2[c*128 + k]*att2[128 + c];
        g_w2a[k] = s;
      }
    }
    return;
  }
  int gtid = b*256 + tid;
  if(gtid < 8192) g_D[gtid] = 0;
  else if(gtid < 8448) g_bn2acc[gtid-8192] = 0.f;
  else if(gtid < 8464) g_bars[gtid-8448] = 0u;
  float s0 = 0.f, q0 = 0.f, s1 = 0.f, q1 = 0.f;
  const float* xr = x + (size_t)b*16*TF;
  for(int r = 0; r < 16; r++){
    float v0 = xr[r*TF + tid];
    float v1 = xr[r*TF + 256 + tid];
    s0 += v0; q0 += v0*v0;
    s1 += v1; q1 += v1*v1;
  }
  g_p1s[b*TF + tid]       = s0;
  g_p1q[b*TF + tid]       = q0;
  g_p1s[b*TF + 256 + tid] = s1;
  g_p1q[b*TF + 256 + tid] = q1;
}

// ---------------- K2: bn1 finalize (0,1) | count_src (2..257) ----------------
__global__ __launch_bounds__(256) void k_fin_count(const float* __restrict__ g,
                                                   const float* __restrict__ b,
                                                   const int* __restrict__ e){
  int blk = blockIdx.x, tid = threadIdx.x;
  if(blk < 2){
    int c = blk*256 + tid;
    float s = 0.f, q = 0.f;
    for(int k = 0; k < 512; k++){
      s += g_p1s[k*TF + c];
      q += g_p1q[k*TF + c];
    }
    float m = s/(float)Nn;
    float v = q/(float)Nn - m*m; if(v < 0.f) v = 0.f;
    float rs = rsqrtf(v + BN_EPS);
    float sc = g[c]*rs;
    g_bn1s[c] = sc; g_bn1b[c] = b[c] - m*sc;
  } else {
    int i = (blk-2)*256 + tid;
    if(i < NNZ) atomicAdd(&g_D[e[i]], 1);
  }
}

// ---------------- K3: bn1_apply (bf16) | scan_D ----------------
__global__ __launch_bounds__(256) void k_apply_scan(const float* __restrict__ x){
  int blk = blockIdx.x, tid = threadIdx.x;
  if(blk < 16384){
    int i = blk*256 + tid;
    int c = i & (TF-1);
    int n = i >> 9;
    int t = c >> 4, f = c & 15;
    g_inxb[(t*Nn + n)*Ff + f] = f2bf(x[i]*g_bn1s[c] + g_bn1b[c]);
  } else {
    __shared__ int part[256];
    int s = 0;
    for(int j = 0; j < 32; j++) s += g_D[tid*32 + j];
    part[tid] = s; __syncthreads();
    if(tid == 0){
      int run = 0;
      for(int i = 0; i < 256; i++){ int v = part[i]; part[i] = run; run += v; }
      g_rowptr[Nn] = run;
    }
    __syncthreads();
    int off = part[tid];
    for(int j = 0; j < 32; j++){
      int idx = tid*32 + j;
      g_rowptr[idx] = off; g_cursor[idx] = off;
      off += g_D[idx];
    }
  }
}

// ---------------- K4: GRU (0..511, + q epilogue) | fill_csr (512..767) ----------------
__global__ __launch_bounds__(256) void k_gru_fill(const float* __restrict__ Wih,
                                                  const float* __restrict__ Whh,
                                                  const float* __restrict__ bih,
                                                  const float* __restrict__ bhh,
                                                  const float* __restrict__ Wq,
                                                  const int* __restrict__ e){
  __shared__ __align__(16) short sH[2][16][136];
  int tid = threadIdx.x;
  if(blockIdx.x >= 512){
    int i = (blockIdx.x - 512)*256 + tid;
    if(i < NNZ){
      int pos = atomicAdd(&g_cursor[e[i]], 1);
      g_eidx[pos] = i;
    }
    return;
  }
  int w = tid >> 6, lane = tid & 63;
  int nlo = lane & 15, quad = lane >> 4;
  int n0 = blockIdx.x*16;

  for(int i = tid; i < 2*16*136; i += 256) (&sH[0][0][0])[i] = 0;

  bf8_t Bh[6][4];
  for(int i = 0; i < 6; i++){
    int c = 16*(w + 4*i) + nlo;
    const float* wr = Whh + c*Hh;
    for(int kk = 0; kk < 4; kk++){
      int k0 = kk*32 + quad*8;
      bf8_t f;
      #pragma unroll
      for(int j = 0; j < 8; j++) f[j] = f2bf(wr[k0 + j]);
      Bh[i][kk] = f;
    }
  }
  bf8_t Bx[6];
  for(int i = 0; i < 6; i++){
    int c = 16*(w + 4*i) + nlo;
    bf8_t f;
    #pragma unroll
    for(int j = 0; j < 8; j++){
      int k = quad*8 + j;
      f[j] = (k < Ff) ? f2bf(Wih[c*Ff + k]) : (short)0;
    }
    Bx[i] = f;
  }
  float biasRZ[4];
  for(int i = 0; i < 4; i++){
    int c = 16*(w + 4*i) + nlo;
    biasRZ[i] = bih[c] + bhh[c];
  }
  float bihn[2], bhhn[2];
  for(int j = 0; j < 2; j++){
    int g = 16*(w + 4*j) + nlo;
    bihn[j] = bih[256 + g];
    bhhn[j] = bhh[256 + g];
  }
  float hreg[2][4] = {};

  bf8_t xbuf;
  #pragma unroll
  for(int j = 0; j < 8; j++) xbuf[j] = 0;
  if(quad < 2)
    xbuf = *(const bf8_t*)(g_inxb + ((size_t)(0*Nn + n0 + nlo))*Ff + quad*8);
  __syncthreads();

  int cprow = tid >> 4, cpc8 = tid & 15;

  for(int t = 0; t < Tt; t++){
    int cur = t & 1, nxt = cur ^ 1;

    if(t > 0){
      bf8_t hv8 = *(const bf8_t*)&sH[cur][cprow][cpc8*8];
      *(bf8_t*)(g_hsb + ((size_t)(n0 + cprow)*Tt + (t-1))*Hh + cpc8*8) = hv8;
    }
    bf8_t xnbuf;
    #pragma unroll
    for(int j = 0; j < 8; j++) xnbuf[j] = 0;
    if(t+1 < Tt && quad < 2)
      xnbuf = *(const bf8_t*)(g_inxb + ((size_t)((t+1)*Nn + n0 + nlo))*Ff + quad*8);

    f4_t acc[6];
    f4_t xnacc[2];
    #pragma unroll
    for(int i = 0; i < 4; i++){ f4_t z4; z4[0]=z4[1]=z4[2]=z4[3]=biasRZ[i]; acc[i]=z4; }
    #pragma unroll
    for(int i = 4; i < 6; i++){ f4_t z4; z4[0]=z4[1]=z4[2]=z4[3]=0.f; acc[i]=z4; }
    #pragma unroll
    for(int j = 0; j < 2; j++){ f4_t z4; z4[0]=z4[1]=z4[2]=z4[3]=bihn[j]; xnacc[j]=z4; }

    #pragma unroll
    for(int i = 0; i < 4; i++) acc[i] = MFMA16(xbuf, Bx[i], acc[i]);
    #pragma unroll
    for(int j = 0; j < 2; j++) xnacc[j] = MFMA16(xbuf, Bx[4+j], xnacc[j]);

    #pragma unroll
    for(int kk = 0; kk < 4; kk++){
      bf8_t ah = *(const bf8_t*)&sH[cur][nlo][kk*32 + quad*8];
      #pragma unroll
      for(int i = 0; i < 6; i++)
        acc[i] = MFMA16(ah, Bh[i][kk], acc[i]);
    }

    short shi2[2][4];
    #pragma unroll
    for(int j = 0; j < 2; j++){
      #pragma unroll
      for(int rr = 0; rr < 4; rr++){
        float r  = fsigmoid(acc[j][rr]);
        float z  = fsigmoid(acc[2+j][rr]);
        float hn = acc[4+j][rr] + bhhn[j];
        float arg = xnacc[j][rr] + r*hn;
        float nn = ftanh(arg);
        float hv = nn + z*(hreg[j][rr] - nn);
        hreg[j][rr] = hv;
        shi2[j][rr] = f2bf(hv);
      }
    }
    #pragma unroll
    for(int j = 0; j < 2; j++){
      int g = 16*(w + 4*j) + nlo;
      #pragma unroll
      for(int rr = 0; rr < 4; rr++)
        sH[nxt][quad*4 + rr][g] = shi2[j][rr];
    }
    __syncthreads();
    xbuf = xnbuf;
  }
  {
    bf8_t hv8 = *(const bf8_t*)&sH[0][cprow][cpc8*8];
    *(bf8_t*)(g_hsb + ((size_t)(n0 + cprow)*Tt + (Tt-1))*Hh + cpc8*8) = hv8;
  }
  // q epilogue
  #pragma unroll
  for(int ct2 = 0; ct2 < 2; ct2++){
    int ct = w + 4*ct2;
    f4_t qacc; qacc[0]=qacc[1]=qacc[2]=qacc[3]=0.f;
    #pragma unroll
    for(int kk = 0; kk < 4; kk++){
      const float* wr = Wq + (16*ct + nlo)*Hh + kk*32 + quad*8;
      float4 w0 = *(const float4*)wr;
      float4 w1 = *(const float4*)(wr + 4);
      bf8_t bf;
      bf[0]=f2bf(w0.x); bf[1]=f2bf(w0.y); bf[2]=f2bf(w0.z); bf[3]=f2bf(w0.w);
      bf[4]=f2bf(w1.x); bf[5]=f2bf(w1.y); bf[6]=f2bf(w1.z); bf[7]=f2bf(w1.w);
      bf8_t ah = *(const bf8_t*)&sH[0][nlo][kk*32 + quad*8];
      qacc = MFMA16(ah, bf, qacc);
    }
    #pragma unroll
    for(int rr = 0; rr < 4; rr++)
      g_q[(n0 + quad*4 + rr)*Hh + 16*ct + nlo] = qacc[rr];
  }
}

// ---------------- K5: mega-kernel (10 fused phases, manual grid barrier) ----------------
union MegaSmem {
  struct { float shHs[2][32][132]; float shQ[2][128]; float shSc[2][32]; float shWt[2][32]; } am;
  struct { float As[64][65]; float Bs[64][65]; float r1[16][64]; float r2[16][64]; } go;
  struct { float bs[128]; float bb[128]; int srcs[2][32]; float w1as[512]; float prt[4][4]; } h1;
  struct { float bs2[128]; float bb2[128]; float w1xs[512]; } h1m;   // bs2/bb2 alias bs/bb
  struct { int srcs1[2][32]; float al1[2][32][4]; } e1;
  struct { int srcs2[2][32]; float w2as[128]; float prt2[4]; } h2;
  struct { float w2xs[128]; } h2m;
  struct { int srcs3[2][32]; float al2[2][32]; } e2;
  struct { float sh[2][128]; } n2;
};

__global__ __launch_bounds__(256, 2) void k_mega(const int* __restrict__ e,
                                                 const float* __restrict__ ae,
                                                 const float* __restrict__ ab,
                                                 const float* __restrict__ Wout,
                                                 const float* __restrict__ g2,
                                                 const float* __restrict__ b2,
                                                 const float* __restrict__ W1,
                                                 const float* __restrict__ W2,
                                                 const float* __restrict__ bias1,
                                                 const float* __restrict__ bias2,
                                                 const float* __restrict__ Wo,
                                                 const float* __restrict__ bo,
                                                 float* __restrict__ out_nf,
                                                 float* __restrict__ out_x,
                                                 float* __restrict__ out_o){
  __shared__ MegaSmem sm;
  int blk = blockIdx.x, tid = threadIdx.x;
  int half = tid >> 7, ht = tid & 127;

  // ---- P4: attn_mid (4096 units, 2 nodes each) ----
  for(int u = blk; u < 4096; u += MGRID){
    __syncthreads();
    int n = 2*u + half;
    const int4* src = (const int4*)(g_hsb + (size_t)n*Tt*Hh);
    for(int i = ht; i < 512; i += 128){
      int4 v = src[i];
      int t = i >> 4, h0 = (i & 15) << 3;
      float* dst = &sm.am.shHs[half][t][h0];
      int vv[4] = {v.x, v.y, v.z, v.w};
      #pragma unroll
      for(int jj = 0; jj < 4; jj++){
        dst[jj*2]   = bf2f((short)(vv[jj] & 0xffff));
        dst[jj*2+1] = bf2f((short)(vv[jj] >> 16));
      }
    }
    float vq = g_q[n*Hh + ht];
    sm.am.shQ[half][ht] = vq;
    __syncthreads();
    {
      int g4 = ht >> 2, l4 = ht & 3;
      float s = 0.f;
      for(int h = l4; h < 128; h += 4) s += sm.am.shQ[half][h]*sm.am.shHs[half][g4][h];
      s += __shfl_xor(s, 1);
      s += __shfl_xor(s, 2);
      if(l4 == 0) sm.am.shSc[half][g4] = s;
    }
    __syncthreads();
    if(ht < 64){
      float v = (ht < 32) ? sm.am.shSc[half][ht] : -1e30f;
      float m = v;
      for(int o = 16; o > 0; o >>= 1) m = fmaxf(m, __shfl_xor(m, o));
      float e2 = (ht < 32) ? __expf(v - m) : 0.f;
      float s = e2;
      for(int o = 16; o > 0; o >>= 1) s += __shfl_xor(s, o);
      if(ht < 32) sm.am.shWt[half][ht] = e2/s;
    }
    __syncthreads();
    float aev = ae[n], abv = ab[n];
    float acc = 0.f;
    for(int t = 0; t < 32; t++){
      float mix = sm.am.shWt[half][t]*sm.am.shHs[half][t][ht];
      float bt  = __expf(-abv*(float)(31 - t));
      float r2  = aev*mix*bt;
      acc += mix + (r2 > 0.f ? r2 : 0.f);
    }
    g_cmb[n*256 + ht] = acc;
    g_cmb[n*256 + 128 + ht] = vq;
  }
  gsync(0);

  // ---- P5: gemm_out (256 units) ----
  for(int u = blk; u < 256; u += MGRID){
    __syncthreads();
    int bm = (u >> 1)*64, bn = (u & 1)*64;
    int tc = tid & 15, tr = tid >> 4;
    float acc[4][4] = {};
    for(int kt = 0; kt < 256; kt += 64){
      __syncthreads();
      for(int idx = tid; idx < 64*64; idx += 256){
        int r = idx >> 6, c = idx & 63;
        sm.go.As[r][c] = g_cmb[(bm+r)*256 + kt + c];
        sm.go.Bs[r][c] = Wout[(bn+r)*256 + kt + c];
      }
      __syncthreads();
      for(int k = 0; k < 64; k++){
        float av[4], wv[4];
        #pragma unroll
        for(int a = 0; a < 4; a++) av[a] = sm.go.As[tr*4+a][k];
        #pragma unroll
        for(int b = 0; b < 4; b++) wv[b] = sm.go.Bs[tc*4+b][k];
        #pragma unroll
        for(int a = 0; a < 4; a++)
          #pragma unroll
          for(int b = 0; b < 4; b++) acc[a][b] += av[a]*wv[b];
      }
    }
    float cs[4] = {}, cq[4] = {};
    for(int a = 0; a < 4; a++)
      for(int b = 0; b < 4; b++){
        float v = ftanh(acc[a][b]);
        int off = (bm+tr*4+a)*Hh + bn + tc*4 + b;
        g_nfb[off] = f2bf(v);
        out_nf[off] = v;
        cs[b] += v; cq[b] += v*v;
      }
    __syncthreads();
    for(int b = 0; b < 4; b++){ sm.go.r1[tr][tc*4+b] = cs[b]; sm.go.r2[tr][tc*4+b] = cq[b]; }
    __syncthreads();
    if(tid < 64){
      float s = 0.f, s2 = 0.f;
      for(int j = 0; j < 16; j++){ s += sm.go.r1[j][tid]; s2 += sm.go.r2[j][tid]; }
      atomicAdd(&g_bn2acc[bn + tid], s);
      atomicAdd(&g_bn2acc[128 + bn + tid], s2);
    }
  }
  gsync(1);

  // ---- P6: hc1a (2048 units: 0..1023 gather->pe1, 1024..2047 mm0+px1) ----
  for(int u = blk; u < 2048; u += MGRID){
    __syncthreads();
    if(tid < 128){
      float s1 = g_bn2acc[tid], s2 = g_bn2acc[128+tid];
      float m = s1/(float)Nn;
      float v = s2/(float)Nn - m*m; if(v < 0.f) v = 0.f;
      float rs = rsqrtf(v + BN_EPS);
      float sc = g2[tid]*rs;
      sm.h1.bs[tid] = sc; sm.h1.bb[tid] = b2[tid] - m*sc;
    }
    if(u < 1024){
      for(int i = tid; i < 512; i += 256) sm.h1.w1as[i] = g_w1a[i];
      if(tid < 64){
        int sub = tid >> 5, k = tid & 31;
        sm.h1.srcs[sub][k] = e[(2*u + sub) + k*Ee];
      }
      __syncthreads();
      int sub = tid >> 7, c = tid & 127;
      float acc = 0.f;
      for(int k = 0; k < 32; k++) acc += bf2f(g_nfb[sm.h1.srcs[sub][k]*Hh + c]);
      float efv = acc*sm.h1.bs[c] + 32.f*sm.h1.bb[c];
      int wv = tid >> 6, lane = tid & 63;
      #pragma unroll
      for(int hd = 0; hd < HEADS; hd++){
        float p = efv*sm.h1.w1as[hd*Hh + c];
        for(int o = 32; o > 0; o >>= 1) p += __shfl_xor(p, o);
        if(lane == 0) sm.h1.prt[wv][hd] = p;
      }
      __syncthreads();
      if(tid < 8){
        int sb = tid >> 2, hd = tid & 3;
        g_pe1[(2*u + sb)*HEADS + hd] = sm.h1.prt[2*sb][hd] + sm.h1.prt[2*sb+1][hd];
      }
    } else {
      int q = u - 1024;
      int bm = (q >> 3)*64, bn = (q & 7)*64;
      int epi = ((q & 7) == 0);
      if(epi) for(int i = tid; i < 512; i += 256) sm.h1m.w1xs[i] = g_w1x[i];
      __syncthreads();
      int wv = tid >> 6, lane = tid & 63;
      int nlo = lane & 15, quad = lane >> 4;
      int arow = bm + 16*wv + nlo;
      bf8_t a[4]; float av[4][8];
      #pragma unroll
      for(int kk = 0; kk < 4; kk++){
        bf8_t raw = *(const bf8_t*)(g_nfb + (size_t)arow*Hh + kk*32 + quad*8);
        #pragma unroll
        for(int j = 0; j < 8; j++){
          int k = kk*32 + quad*8 + j;
          float t = bf2f(raw[j])*sm.h1.bs[k] + sm.h1.bb[k];
          av[kk][j] = t;
          a[kk][j] = f2bf(t);
        }
      }
      bf8_t Wf[4][4];
      #pragma unroll
      for(int ct = 0; ct < 4; ct++){
        const float* wr0 = W1 + (size_t)(bn + 16*ct + nlo)*Hh;
        #pragma unroll
        for(int kk = 0; kk < 4; kk++){
          const float* wr = wr0 + kk*32 + quad*8;
          float4 w0 = *(const float4*)wr;
          float4 w1v = *(const float4*)(wr + 4);
          bf8_t f;
          f[0]=f2bf(w0.x); f[1]=f2bf(w0.y); f[2]=f2bf(w0.z); f[3]=f2bf(w0.w);
          f[4]=f2bf(w1v.x); f[5]=f2bf(w1v.y); f[6]=f2bf(w1v.z); f[7]=f2bf(w1v.w);
          Wf[ct][kk] = f;
        }
      }
      f4_t acc[4];
      #pragma unroll
      for(int ct = 0; ct < 4; ct++){ f4_t z4; z4[0]=z4[1]=z4[2]=z4[3]=0.f; acc[ct]=z4; }
      #pragma unroll
      for(int ct = 0; ct < 4; ct++)
        #pragma unroll
        for(int kk = 0; kk < 4; kk++)
          acc[ct] = MFMA16(a[kk], Wf[ct][kk], acc[ct]);
      #pragma unroll
      for(int ct = 0; ct < 4; ct++){
        int col = bn + 16*ct + nlo;
        int addr = (col & 127)*4 + (col >> 7);
        #pragma unroll
        for(int rr = 0; rr < 4; rr++)
          g_xwb[(size_t)(bm + 16*wv + quad*4 + rr)*512 + addr] = f2bf(acc[ct][rr]);
      }
      if(epi){
        #pragma unroll
        for(int hd = 0; hd < HEADS; hd++){
          float s = 0.f;
          #pragma unroll
          for(int kk = 0; kk < 4; kk++)
            #pragma unroll
            for(int j = 0; j < 8; j++)
              s += av[kk][j]*sm.h1m.w1xs[hd*Hh + kk*32 + quad*8 + j];
          s += __shfl_xor(s, 16);
          s += __shfl_xor(s, 32);
          if(quad == 0) g_px1[arow*HEADS + hd] = s;
        }
      }
    }
  }
  gsync(2);

  // ---- P7: seg_stats1 (2048 units, 4 nodes each via waves) ----
  for(int u = blk; u < 2048; u += MGRID){
    int wv = tid >> 6, lane = tid & 63;
    int n = 4*u + wv;
    int start = g_rowptr[n], deg = g_rowptr[n+1] - start;
    #pragma unroll
    for(int hd = 0; hd < HEADS; hd++){
      float px = g_px1[n*HEADS + hd];
      float m = -1e30f;
      for(int base = 0; base < deg; base += 64){
        int j = base + lane;
        if(j < deg){
          int d = g_eidx[start+j] & (Ee-1);
          m = fmaxf(m, lrelu02(px + g_pe1[d*HEADS + hd]));
        }
      }
      for(int o = 32; o > 0; o >>= 1) m = fmaxf(m, __shfl_xor(m, o));
      float s = 0.f;
      for(int base = 0; base < deg; base += 64){
        int j = base + lane;
        if(j < deg){
          int d = g_eidx[start+j] & (Ee-1);
          s += expf(lrelu02(px + g_pe1[d*HEADS + hd]) - m);
        }
      }
      for(int o = 32; o > 0; o >>= 1) s += __shfl_xor(s, o);
      if(lane == 0){
        g_m1[n*HEADS + hd] = m;
        g_is1[n*HEADS + hd] = 1.f/(s + 1e-16f);
      }
    }
  }
  gsync(3);

  // ---- P8: eout1 (1024 units, 2 edges each) ----
  for(int u = blk; u < 1024; u += MGRID){
    __syncthreads();
    int d = 2*u + half;
    if(ht < 32) sm.e1.srcs1[half][ht] = e[d + ht*Ee];
    __syncthreads();
    if(ht < 32){
      int src = sm.e1.srcs1[half][ht];
      float4 px = *(const float4*)&g_px1[src*4];
      float4 pm = *(const float4*)&g_m1[src*4];
      float4 pis = *(const float4*)&g_is1[src*4];
      float4 pe = *(const float4*)&g_pe1[d*4];
      sm.e1.al1[half][ht][0] = __expf(lrelu02(px.x + pe.x) - pm.x)*pis.x;
      sm.e1.al1[half][ht][1] = __expf(lrelu02(px.y + pe.y) - pm.y)*pis.y;
      sm.e1.al1[half][ht][2] = __expf(lrelu02(px.z + pe.z) - pm.z)*pis.z;
      sm.e1.al1[half][ht][3] = __expf(lrelu02(px.w + pe.w) - pm.w)*pis.w;
    }
    __syncthreads();
    float acc[4] = {};
    for(int k = 0; k < 32; k++){
      s4_t v = *(const s4_t*)(g_xwb + (size_t)sm.e1.srcs1[half][k]*512 + ht*4);
      float a0 = sm.e1.al1[half][k][0], a1 = sm.e1.al1[half][k][1];
      float a2 = sm.e1.al1[half][k][2], a3 = sm.e1.al1[half][k][3];
      acc[0] += a0*bf2f(v[0]);
      acc[1] += a1*bf2f(v[1]);
      acc[2] += a2*bf2f(v[2]);
      acc[3] += a3*bf2f(v[3]);
    }
    s4_t ov;
    #pragma unroll
    for(int hd = 0; hd < 4; hd++) ov[hd] = f2bf(acc[hd]*(1.f/32.f));
    *(s4_t*)(g_eoutb + (size_t)d*512 + ht*4) = ov;
  }
  gsync(4);

  // ---- P9: node_out1 (4096 units, 2 nodes each; no LDS) ----
  for(int u = blk; u < 4096; u += MGRID){
    int n = 2*u + half, c = ht;
    int start = g_rowptr[n], deg = g_rowptr[n+1] - start;
    float4 px = *(const float4*)&g_px1[n*4];
    float4 pm = *(const float4*)&g_m1[n*4];
    float4 pis = *(const float4*)&g_is1[n*4];
    float acc = 0.f;
    for(int j = 0; j < deg; j++){
      int i = g_eidx[start+j];
      int d = i & (Ee-1);
      float4 pe = *(const float4*)&g_pe1[d*4];
      float a0 = __expf(lrelu02(px.x + pe.x) - pm.x)*pis.x;
      float a1 = __expf(lrelu02(px.y + pe.y) - pm.y)*pis.y;
      float a2 = __expf(lrelu02(px.z + pe.z) - pm.z)*pis.z;
      float a3 = __expf(lrelu02(px.w + pe.w) - pm.w)*pis.w;
      s4_t v = *(const s4_t*)(g_eoutb + (size_t)d*512 + c*4);
      acc += a0*bf2f(v[0]) + a1*bf2f(v[1]) + a2*bf2f(v[2]) + a3*bf2f(v[3]);
    }
    float Dinv = (deg > 0) ? 1.f/(float)deg : 0.f;
    float v = acc*Dinv*0.25f + bias1[c];
    g_x1b[n*Hh + c] = f2bf((v >= 0.f) ? v : 0.2f*v);
  }
  gsync(5);

  // ---- P10: hc2a (1280 units: 0..1023 gather->pb2, 1024..1279 mm2+pa2) ----
  for(int u = blk; u < 1280; u += MGRID){
    __syncthreads();
    if(u < 1024){
      if(tid < 128) sm.h2.w2as[tid] = g_w2a[tid];
      if(tid < 64){
        int sub = tid >> 5, k = tid & 31;
        sm.h2.srcs2[sub][k] = e[(2*u + sub) + k*Ee];
      }
      __syncthreads();
      int sub = tid >> 7, c = tid & 127;
      float acc = 0.f;
      for(int k = 0; k < 32; k++) acc += bf2f(g_x1b[sm.h2.srcs2[sub][k]*Hh + c]);
      int wv = tid >> 6, lane = tid & 63;
      float p = acc*sm.h2.w2as[c];
      for(int o = 32; o > 0; o >>= 1) p += __shfl_xor(p, o);
      if(lane == 0) sm.h2.prt2[wv] = p;
      __syncthreads();
      if(tid < 2) g_pb2[2*u + tid] = sm.h2.prt2[2*tid] + sm.h2.prt2[2*tid+1];
    } else {
      int q = u - 1024;
      int bm = (q >> 1)*64, bn = (q & 1)*64;
      int epi = ((q & 1) == 0);
      if(epi && tid < 128) sm.h2m.w2xs[tid] = g_w2x[tid];
      __syncthreads();
      int wv = tid >> 6, lane = tid & 63;
      int nlo = lane & 15, quad = lane >> 4;
      int arow = bm + 16*wv + nlo;
      bf8_t a[4];
      #pragma unroll
      for(int kk = 0; kk < 4; kk++)
        a[kk] = *(const bf8_t*)(g_x1b + (size_t)arow*Hh + kk*32 + quad*8);
      bf8_t Wf[4][4];
      #pragma unroll
      for(int ct = 0; ct < 4; ct++){
        const float* wr0 = W2 + (size_t)(bn + 16*ct + nlo)*Hh;
        #pragma unroll
        for(int kk = 0; kk < 4; kk++){
          const float* wr = wr0 + kk*32 + quad*8;
          float4 w0 = *(const float4*)wr;
          float4 w1v = *(const float4*)(wr + 4);
          bf8_t f;
          f[0]=f2bf(w0.x); f[1]=f2bf(w0.y); f[2]=f2bf(w0.z); f[3]=f2bf(w0.w);
          f[4]=f2bf(w1v.x); f[5]=f2bf(w1v.y); f[6]=f2bf(w1v.z); f[7]=f2bf(w1v.w);
          Wf[ct][kk] = f;
        }
      }
      f4_t acc[4];
      #pragma unroll
      for(int ct = 0; ct < 4; ct++){ f4_t z4; z4[0]=z4[1]=z4[2]=z4[3]=0.f; acc[ct]=z4; }
      #pragma unroll
      for(int ct = 0; ct < 4; ct++)
        #pragma unroll
        for(int kk = 0; kk < 4; kk++)
          acc[ct] = MFMA16(a[kk], Wf[ct][kk], acc[ct]);
      #pragma unroll
      for(int ct = 0; ct < 4; ct++)
        #pragma unroll
        for(int rr = 0; rr < 4; rr++)
          g_xw2b[(size_t)(bm + 16*wv + quad*4 + rr)*Hh + bn + 16*ct + nlo] = f2bf(acc[ct][rr]);
      if(epi){
        float s = 0.f;
        #pragma unroll
        for(int kk = 0; kk < 4; kk++)
          #pragma unroll
          for(int j = 0; j < 8; j++)
            s += bf2f(a[kk][j])*sm.h2m.w2xs[kk*32 + quad*8 + j];
        s += __shfl_xor(s, 16);
        s += __shfl_xor(s, 32);
        if(quad == 0) g_pa2[arow] = s;
      }
    }
  }
  gsync(6);

  // ---- P11: seg_stats2 (2048 units, 4 nodes each) ----
  for(int u = blk; u < 2048; u += MGRID){
    int wv = tid >> 6, lane = tid & 63;
    int n = 4*u + wv;
    int start = g_rowptr[n], deg = g_rowptr[n+1] - start;
    float px = g_pa2[n];
    float m = -1e30f;
    for(int base = 0; base < deg; base += 64){
      int j = base + lane;
      if(j < deg){
        int d = g_eidx[start+j] & (Ee-1);
        m = fmaxf(m, lrelu02(px + g_pb2[d]));
      }
    }
    for(int o = 32; o > 0; o >>= 1) m = fmaxf(m, __shfl_xor(m, o));
    float s = 0.f;
    for(int base = 0; base < deg; base += 64){
      int j = base + lane;
      if(j < deg){
        int d = g_eidx[start+j] & (Ee-1);
        s += expf(lrelu02(px + g_pb2[d]) - m);
      }
    }
    for(int o = 32; o > 0; o >>= 1) s += __shfl_xor(s, o);
    if(lane == 0){
      g_m2[n] = m;
      g_is2[n] = 1.f/(s + 1e-16f);
    }
  }
  gsync(7);

  // ---- P12: eout2 (1024 units, 2 edges each) ----
  for(int u = blk; u < 1024; u += MGRID){
    __syncthreads();
    int d = 2*u + half;
    if(ht < 32) sm.e2.srcs3[half][ht] = e[d + ht*Ee];
    __syncthreads();
    if(ht < 32){
      int src = sm.e2.srcs3[half][ht];
      sm.e2.al2[half][ht] = __expf(lrelu02(g_pa2[src] + g_pb2[d]) - g_m2[src])*g_is2[src];
    }
    __syncthreads();
    float acc = 0.f;
    for(int k = 0; k < 32; k++) acc += sm.e2.al2[half][k]*bf2f(g_xw2b[sm.e2.srcs3[half][k]*Hh + ht]);
    g_eout2b[d*Hh + ht] = f2bf(acc*(1.f/32.f));
  }
  gsync(8);

  // ---- P13: node_out2 + final projection (4096 units, 2 nodes each) ----
  for(int u = blk; u < 4096; u += MGRID){
    __syncthreads();
    int n = 2*u + half, c = ht;
    int start = g_rowptr[n], deg = g_rowptr[n+1] - start;
    float px = g_pa2[n], m2 = g_m2[n], is2 = g_is2[n];
    float acc = 0.f;
    for(int j = 0; j < deg; j++){
      int i = g_eidx[start+j];
      int d = i & (Ee-1);
      float a = __expf(lrelu02(px + g_pb2[d]) - m2)*is2;
      acc += a*bf2f(g_eout2b[d*Hh + c]);
    }
    float Dinv = (deg > 0) ? 1.f/(float)deg : 0.f;
    float v = acc*Dinv + bias2[c];
    v = (v >= 0.f) ? v : 0.2f*v;
    out_x[n*Hh + c] = v;
    __syncthreads();
    sm.n2.sh[half][c] = v*Wo[c];
    __syncthreads();
    for(int o = 64; o > 0; o >>= 1){
      if(c < o) sm.n2.sh[half][c] += sm.n2.sh[half][c+o];
      __syncthreads();
    }
    if(c == 0){
      float r = sm.n2.sh[half][0] + bo[0];
      r = (r >= 0.f) ? r : 0.01f*r;
      out_o[n] = r;
    }
  }
}

extern "C" void kernel_launch(void* const* d_in, const int* in_sizes, int n_in,
                              void* d_out, int out_size, void* d_ws, size_t ws_size,
                              hipStream_t stream){
  const float* price = (const float*)d_in[0];
  const int*   e     = (const int*)  d_in[1];
  const float* bn1_g = (const float*)d_in[2];
  const float* bn1_b = (const float*)d_in[3];
  const float* W_ih  = (const float*)d_in[4];
  const float* W_hh  = (const float*)d_in[5];
  const float* b_ih  = (const float*)d_in[6];
  const float* b_hh  = (const float*)d_in[7];
  const float* Wq    = (const float*)d_in[8];
  const float* Wout  = (const float*)d_in[9];
  const float* ae    = (const float*)d_in[10];
  const float* ab    = (const float*)d_in[11];
  const float* bn2_g = (const float*)d_in[12];
  const float* bn2_b = (const float*)d_in[13];
  const float* W1    = (const float*)d_in[14];
  const float* att1  = (const float*)d_in[15];
  const float* bias1 = (const float*)d_in[16];
  const float* W2    = (const float*)d_in[17];
  const float* att2  = (const float*)d_in[18];
  const float* bias2 = (const float*)d_in[19];
  const float* Wo    = (const float*)d_in[20];
  const float* bo    = (const float*)d_in[21];

  float* out_nf = (float*)d_out;
  float* out_x  = out_nf + Nn*Hh;
  float* out_o  = out_nf + 2*Nn*Hh;

  k_pre<<<514, 256, 0, stream>>>(price, W1, att1, W2, att2);
  k_fin_count<<<258, 256, 0, stream>>>(bn1_g, bn1_b, e);
  k_apply_scan<<<16385, 256, 0, stream>>>(price);
  k_gru_fill<<<768, 256, 0, stream>>>(W_ih, W_hh, b_ih, b_hh, Wq, e);
  k_mega<<<MGRID, 256, 0, stream>>>(e, ae, ab, Wout, bn2_g, bn2_b, W1, W2,
                                    bias1, bias2, Wo, bo, out_nf, out_x, out_o);

  (void)in_sizes; (void)n_in; (void)out_size; (void)d_ws; (void)ws_size;
}